// Round 4
// baseline (70.723 us; speedup 1.0000x reference)
//
#include <hip/hip_runtime.h>

// Problem: B=16, F=1024 (32x32 image), Ci=64, Co=64, K=4, R=1.
// out[b, h*32+w, co] = log( sum_ci exp(ll[b,f,ci]) * exp(logits[co,ci,kh,kw]) )
//                      - log( sum_ci exp(logits[co,ci,kh,kw]) ),  kh=h%4, kw=w%4.
#define CI 64
#define CO 64
#define F_ 1024

__device__ __forceinline__ float bcast(float v, int l) {
    return __int_as_float(__builtin_amdgcn_readlane(__float_as_int(v), l));
}

__device__ __forceinline__ unsigned int bf16_rne(float x) {
    const unsigned int u = __float_as_uint(x);
    return (u + 0x7fffu + ((u >> 16) & 1u)) >> 16;   // x>0 always, no NaN
}

// Single fused kernel: 512 blocks x 512 threads (8 waves).
// Block handles patterns half*8..half*8+7 (one per wave) for 4 positions/wave.
__global__ __launch_bounds__(512, 4) void fused_kernel(
    const float* __restrict__ ll, const float* __restrict__ logits,
    float* __restrict__ out)
{
    // [pat_local][ci/2][co] : 2 bf16 exp-weights packed per uint — 64 KB
    __shared__ unsigned int Wb[8][32][64];

    const int tid   = threadIdx.x;
    const int lane  = tid & 63;
    const int wv    = tid >> 6;            // 0..7
    const int bid   = blockIdx.x;          // 0..511
    const int half  = bid & 1;             // pats half*8 .. half*8+7
    const int chunk = bid >> 1;            // 0..255

    const int pat = half * 8 + wv;         // this wave's pattern
    const int kh = pat >> 2, kw = pat & 3;

    // ---- issue 4 position loads first (HBM latency hidden under Phase A) ----
    int   idx[4];
    float p[4];
    #pragma unroll
    for (int j = 0; j < 4; ++j) {
        const int pr = chunk * 4 + j;      // 0..1023 = b*64 + oh*8 + ow
        const int b  = pr >> 6;
        const int oh = (pr >> 3) & 7;
        const int ow = pr & 7;
        const int f  = (oh * 4 + kh) * 32 + (ow * 4 + kw);
        idx[j] = (b * F_ + f) * CI + lane; // coalesced 256 B / wave
        p[j]   = ll[idx[j]];
    }

    // ---- Phase A: co = lane; this wave fills ci block [8wv, 8wv+8) for all 8 pats ----
    {
        const float* base = logits + lane * (CI * 16) + half * 8;   // [co][ci][pat16]
        #pragma unroll
        for (int cc = 0; cc < 8; cc += 2) {
            const int ci0 = 8 * wv + cc;                 // even
            const float4 A = *reinterpret_cast<const float4*>(base + ci0 * 16);       // ci0, pl 0..3
            const float4 Bv = *reinterpret_cast<const float4*>(base + ci0 * 16 + 4);  // ci0, pl 4..7
            const float4 Cv = *reinterpret_cast<const float4*>(base + ci0 * 16 + 16); // ci1, pl 0..3
            const float4 D = *reinterpret_cast<const float4*>(base + ci0 * 16 + 20);  // ci1, pl 4..7
            const float ea[8] = {A.x, A.y, A.z, A.w, Bv.x, Bv.y, Bv.z, Bv.w};
            const float eb[8] = {Cv.x, Cv.y, Cv.z, Cv.w, D.x, D.y, D.z, D.w};
            #pragma unroll
            for (int pl = 0; pl < 8; ++pl) {
                const unsigned int lo = bf16_rne(__expf(ea[pl]));
                const unsigned int hi = bf16_rne(__expf(eb[pl]));
                Wb[pl][4 * wv + (cc >> 1)][lane] = lo | (hi << 16);  // bank=co%32: 2-way, free
            }
        }
    }
    __syncthreads();

    // ---- Phase B: my pattern's weights -> registers (lane = co) ----
    float wreg[CI];
    #pragma unroll
    for (int g = 0; g < 32; ++g) {
        const unsigned int u = Wb[wv][g][lane];          // bank=co%32: 2-way, free
        wreg[2 * g]     = __uint_as_float(u << 16);
        wreg[2 * g + 1] = __uint_as_float(u & 0xffff0000u);
    }

    // lsum from the SAME quantized weights (num/den quantization cancels)
    float ts[8];
    #pragma unroll
    for (int i = 0; i < 8; ++i)
        ts[i] = (wreg[i] + wreg[i + 8]) + (wreg[i + 16] + wreg[i + 24])
              + (wreg[i + 32] + wreg[i + 40]) + (wreg[i + 48] + wreg[i + 56]);
    const float lsum = __logf(((ts[0] + ts[1]) + (ts[2] + ts[3]))
                            + ((ts[4] + ts[5]) + (ts[6] + ts[7])));

    // ---- exp(p), then readlane-broadcast FMA over ci ----
    #pragma unroll
    for (int j = 0; j < 4; ++j) p[j] = __expf(p[j]);

    float a0[4] = {0.f,0.f,0.f,0.f}, a1[4] = {0.f,0.f,0.f,0.f};
    float a2[4] = {0.f,0.f,0.f,0.f}, a3[4] = {0.f,0.f,0.f,0.f};
    #pragma unroll
    for (int ci = 0; ci < CI; ci += 4) {
        #pragma unroll
        for (int j = 0; j < 4; ++j) {
            a0[j] = fmaf(bcast(p[j], ci + 0), wreg[ci + 0], a0[j]);
            a1[j] = fmaf(bcast(p[j], ci + 1), wreg[ci + 1], a1[j]);
            a2[j] = fmaf(bcast(p[j], ci + 2), wreg[ci + 2], a2[j]);
            a3[j] = fmaf(bcast(p[j], ci + 3), wreg[ci + 3], a3[j]);
        }
    }
    #pragma unroll
    for (int j = 0; j < 4; ++j)
        out[idx[j]] = __logf((a0[j] + a1[j]) + (a2[j] + a3[j])) - lsum;  // coalesced
}

extern "C" void kernel_launch(void* const* d_in, const int* in_sizes, int n_in,
                              void* d_out, int out_size, void* d_ws, size_t ws_size,
                              hipStream_t stream) {
    const float* ll     = (const float*)d_in[0];
    const float* logits = (const float*)d_in[1];
    float* out = (float*)d_out;
    fused_kernel<<<dim3(512), dim3(512), 0, stream>>>(ll, logits, out);
}

// Round 5
// 65.536 us; speedup vs baseline: 1.0792x; 1.0792x over previous
//
#include <hip/hip_runtime.h>

// Problem: B=16, F=1024 (32x32 image), Ci=64, Co=64, K=4, R=1.
// out[b, h*32+w, co] = log( sum_ci softmax_ci(logits[:,:,kh,kw])[co,ci] * exp(ll[b,f,ci]) )
//   where kh=h%4, kw=w%4.  (log_softmax weights folded: num/den normalization done in prep)
#define CI 64
#define CO 64
#define F_ 1024
#define KK 4
#define NPAT 16

__device__ __forceinline__ float bcast(float v, int l) {
    return __int_as_float(__builtin_amdgcn_readlane(__float_as_int(v), l));
}

// ---------------- kernel 1: prep (16 blocks, one per pattern) ----------------
// En[pat][g][co][k] = exp(logits[co][ci=4g+k][kh][kw]) / sum_ci exp(...)
// float4-friendly layout for main's coalesced b128 weight loads.
__global__ __launch_bounds__(256) void prep_kernel(
    const float* __restrict__ logits, float* __restrict__ En)
{
    __shared__ float part[4 * CO];
    const int pat = blockIdx.x;              // 0..15
    const int t   = threadIdx.x;
    const int co  = t & 63;
    const int s   = t >> 6;                  // 0..3
    const float* lg = logits + co * (CI * KK * KK) + pat;   // stride ci = 16 floats

    // thread covers ci groups g ∈ {s, s+4, s+8, s+12}, 4 ci each
    float e[16];
    float psum = 0.f;
    #pragma unroll
    for (int m = 0; m < 4; ++m) {
        const int g = s + 4 * m;
        #pragma unroll
        for (int k = 0; k < 4; ++k) {
            const float v = __expf(lg[(4 * g + k) * (KK * KK)]);
            e[4 * m + k] = v;
            psum += v;
        }
    }
    part[s * CO + co] = psum;
    __syncthreads();
    const float inv = 1.f / ((part[co] + part[CO + co]) + (part[2 * CO + co] + part[3 * CO + co]));

    float4* dst = reinterpret_cast<float4*>(En + pat * (CI * CO));
    #pragma unroll
    for (int m = 0; m < 4; ++m) {
        const int g = s + 4 * m;
        float4 o;
        o.x = e[4 * m + 0] * inv; o.y = e[4 * m + 1] * inv;
        o.z = e[4 * m + 2] * inv; o.w = e[4 * m + 3] * inv;
        dst[g * CO + co] = o;                // fully coalesced float4 stores
    }
}

// ---------------- kernel 2: main (1024 blocks, no LDS, no barriers) ----------------
// lane = co (compute/store) = ci (ll load). Each wave: 4 positions of one pattern.
__global__ __launch_bounds__(256, 4) void main_kernel(
    const float* __restrict__ ll, const float* __restrict__ En,
    float* __restrict__ out)
{
    const int tid   = threadIdx.x;
    const int lane  = tid & 63;
    const int wv    = tid >> 6;
    const int bid   = blockIdx.x;            // 1024
    const int pat   = bid & (NPAT - 1);
    const int chunk = bid >> 4;              // 0..63
    const int kh = pat >> 2, kw = pat & 3;

    // ---- issue the 4 HBM loads first (longest latency) ----
    int   idx[4];
    float p[4];
    #pragma unroll
    for (int j = 0; j < 4; ++j) {
        const int pr = (chunk << 4) + (wv << 2) + j;   // b*64 + oh*8 + ow
        const int b  = pr >> 6;
        const int oh = (pr >> 3) & 7;
        const int ow = pr & 7;
        const int f  = (oh * 4 + kh) * 32 + (ow * 4 + kw);
        idx[j] = (b * F_ + f) * CI + lane;             // coalesced 256 B / wave
        p[j]   = ll[idx[j]];
    }

    // ---- weights: 16 coalesced float4 loads (L2-hot), lane = co ----
    float4 wv4[16];
    const float4* Ep4 = reinterpret_cast<const float4*>(En + pat * (CI * CO)) + lane;
    #pragma unroll
    for (int g = 0; g < 16; ++g) wv4[g] = Ep4[g * CO];
    float wreg[CI];
    #pragma unroll
    for (int g = 0; g < 16; ++g) {
        wreg[4 * g + 0] = wv4[g].x; wreg[4 * g + 1] = wv4[g].y;
        wreg[4 * g + 2] = wv4[g].z; wreg[4 * g + 3] = wv4[g].w;
    }

    // ---- exp, then broadcast via v_readlane (VALU pipe, no LDS) ----
    #pragma unroll
    for (int j = 0; j < 4; ++j) p[j] = __expf(p[j]);

    float a0[4] = {0.f,0.f,0.f,0.f}, a1[4] = {0.f,0.f,0.f,0.f};
    float a2[4] = {0.f,0.f,0.f,0.f}, a3[4] = {0.f,0.f,0.f,0.f};
    #pragma unroll
    for (int ci = 0; ci < CI; ci += 4) {
        #pragma unroll
        for (int j = 0; j < 4; ++j) {
            a0[j] = fmaf(bcast(p[j], ci + 0), wreg[ci + 0], a0[j]);
            a1[j] = fmaf(bcast(p[j], ci + 1), wreg[ci + 1], a1[j]);
            a2[j] = fmaf(bcast(p[j], ci + 2), wreg[ci + 2], a2[j]);
            a3[j] = fmaf(bcast(p[j], ci + 3), wreg[ci + 3], a3[j]);
        }
    }
    #pragma unroll
    for (int j = 0; j < 4; ++j)
        out[idx[j]] = __logf((a0[j] + a1[j]) + (a2[j] + a3[j]));   // weights pre-normalized
}

extern "C" void kernel_launch(void* const* d_in, const int* in_sizes, int n_in,
                              void* d_out, int out_size, void* d_ws, size_t ws_size,
                              hipStream_t stream) {
    const float* ll     = (const float*)d_in[0];
    const float* logits = (const float*)d_in[1];
    float* out = (float*)d_out;
    float* En  = (float*)d_ws;               // 16*64*64 floats = 256 KB
    prep_kernel<<<dim3(NPAT), dim3(256), 0, stream>>>(logits, En);
    main_kernel<<<dim3(1024), dim3(256), 0, stream>>>(ll, En, out);
}